// Round 18
// baseline (108.859 us; speedup 1.0000x reference)
//
#include <hip/hip_runtime.h>
#include <math.h>

typedef _Float16 f16;
typedef _Float16 f16x4 __attribute__((ext_vector_type(4)));
typedef _Float16 f16x8 __attribute__((ext_vector_type(8)));
typedef float f32x4 __attribute__((ext_vector_type(4)));

#define S_TOTAL 16384
#define N_NODES 512
#define N_PIPES 1024
#define N_DEM   256
#define HIDDEN  64
#define T_SCALE 256.0f   // t = (supply - hL)/T_SCALE; H *= T_SCALE

// direct HBM -> LDS, 16B per lane (wave writes base + lane*16, LINEAR dest)
#define GLOAD16(gsrc, ldst) \
    __builtin_amdgcn_global_load_lds((const __attribute__((address_space(1))) void*)(gsrc), \
                                     (__attribute__((address_space(3))) void*)(ldst), 16, 0, 0)
#define SBAR()  __builtin_amdgcn_s_barrier()
#define FENCE() asm volatile("" ::: "memory")
#define WAITN(n) asm volatile("s_waitcnt vmcnt(" #n ")" ::: "memory")

// f32 -> fp8 e5m2 (bf8): RNE to high byte of f16 bit pattern
__device__ __forceinline__ unsigned char f32_to_bf8(float x) {
    unsigned short h = __builtin_bit_cast(unsigned short, (f16)x);
    unsigned short r = (unsigned short)(h + 0x7F + ((h >> 8) & 1));
    return (unsigned char)(r >> 8);
}

// ================= fused prep ==================================================
// blocks [0,256):     MLP (4 waves/block, 1 pipe/wave) + d_out zero (block 0)
// blocks [256,384):   transpose M -> MT16 (f16 [pipe][node])
// blocks [384,1152):  grid-stride bulk conversions + gathers
// blocks [1152,1280): G16[i][p] = sum_n M[n][i]*inv[n][p]  (f16, from f32 direct)
__global__ __launch_bounds__(256) void prep_all(
    const float* __restrict__ W1, const float* __restrict__ b1,
    const float* __restrict__ W2, const float* __restrict__ b2,
    const float* __restrict__ W3, const float* __restrict__ b3,
    const float* __restrict__ base,
    const float* __restrict__ L, const float* __restrict__ dpipe,
    const float* __restrict__ Cw,
    const float* __restrict__ Mf, const float* __restrict__ inv,
    const float* __restrict__ A0, const float* __restrict__ D,
    const int* __restrict__ dmap,
    float* __restrict__ net, float* __restrict__ lKc,
    f16* __restrict__ MT16, unsigned char* __restrict__ inv8,
    f16* __restrict__ A016, unsigned char* __restrict__ D8,
    f16* __restrict__ DI16, unsigned char* __restrict__ IDXT8,
    f16* __restrict__ G16,
    float* __restrict__ out, int out_size)
{
    __shared__ __align__(16) f16 GAs[128][72];
    __shared__ __align__(16) f16 GBs[64][72];
    const int b = blockIdx.x, t = threadIdx.x;
    if (b < 256) {
        if (b == 0) for (int i = t; i < out_size; i += 256) out[i] = 0.f;
        const int wid = t >> 6, k = t & 63;
        const int p = b * 4 + wid;
        const float x = (float)p;
        float h1 = tanhf(x * W1[k] + b1[k]);
        float acc = b2[k];
        #pragma unroll
        for (int j = 0; j < HIDDEN; ++j) {
            float hj = __shfl(h1, j, 64);
            acc = fmaf(hj, W2[j * HIDDEN + k], acc);
        }
        float partial = tanhf(acc) * W3[k];
        #pragma unroll
        for (int off = 32; off > 0; off >>= 1) partial += __shfl_down(partial, off, 64);
        if (k == 0) {
            net[p] = base[p] + partial + b3[0];
            lKc[p] = log2f(10.667f) - 1.852f * log2f(Cw[p]) - 4.871f * log2f(dpipe[p]) + log2f(L[p]);
        }
        return;
    }
    if (b < 384) {   // transpose M -> MT16
        f16 (*tile)[72] = GBs;
        const int i2 = b - 256;
        const int bx = i2 & 15, by = i2 >> 4;   // 16 x 8 tiles of 64x64
        const int r0 = by * 64, c0 = bx * 64;
        const int lr = t / 16, lc4 = (t % 16) * 4;
        #pragma unroll
        for (int i = 0; i < 4; ++i) {
            int r = lr + i * 16;
            float4 v = *(const float4*)(Mf + (size_t)(r0 + r) * N_PIPES + c0 + lc4);
            tile[lc4 + 0][r] = (f16)v.x; tile[lc4 + 1][r] = (f16)v.y;
            tile[lc4 + 2][r] = (f16)v.z; tile[lc4 + 3][r] = (f16)v.w;
        }
        __syncthreads();
        const int wrow = t / 4, wc16 = (t % 4) * 16;
        *(f16x8*)(MT16 + (size_t)(c0 + wrow) * N_NODES + r0 + wc16)     = *(f16x8*)&tile[wrow][wc16];
        *(f16x8*)(MT16 + (size_t)(c0 + wrow) * N_NODES + r0 + wc16 + 8) = *(f16x8*)&tile[wrow][wc16 + 8];
        return;
    }
    if (b < 1152) {  // bulk conversions + gathers
        const int tid = (b - 384) * 256 + t;
        const int np = 768 * 256;
        for (int i = tid; i < (N_NODES * N_PIPES) / 4; i += np) {
            float4 v = ((const float4*)inv)[i];
            uchar4 v8 = {f32_to_bf8(v.x), f32_to_bf8(v.y), f32_to_bf8(v.z), f32_to_bf8(v.w)};
            ((uchar4*)inv8)[i] = v8;
            float4 w = ((const float4*)A0)[i];
            ((f16x4*)A016)[i] = (f16x4){(f16)w.x, (f16)w.y, (f16)w.z, (f16)w.w};
        }
        for (int i = tid; i < (S_TOTAL * N_DEM) / 4; i += np) {
            float4 v = ((const float4*)D)[i];
            uchar4 o = {f32_to_bf8(v.x), f32_to_bf8(v.y), f32_to_bf8(v.z), f32_to_bf8(v.w)};
            ((uchar4*)D8)[i] = o;
        }
        for (int i = tid; i < N_DEM * (N_PIPES / 4); i += np) {
            int j = i >> 8, p0 = (i & 255) * 4;
            float4 v = *(const float4*)(inv + (size_t)dmap[j] * N_PIPES + p0);
            *(f16x4*)(DI16 + (size_t)j * N_PIPES + p0) = (f16x4){(f16)v.x, (f16)v.y, (f16)v.z, (f16)v.w};
        }
        for (int i = tid; i < N_PIPES * (N_DEM / 4); i += np) {
            int p = i >> 6, j0 = (i & 63) * 4;
            uchar4 o;
            #pragma unroll
            for (int u = 0; u < 4; ++u)
                o[u] = f32_to_bf8(inv[(size_t)dmap[j0 + u] * N_PIPES + p]);
            *(uchar4*)(IDXT8 + (size_t)p * N_DEM + j0) = o;
        }
        return;
    }
    // ---- G16 rider: tile 128 i x 64 p, K=512 over n; operands transposed from f32
    {
        const int bb = b - 1152;
        const int i0 = (bb >> 4) * 128, p0 = (bb & 15) * 64;
        const int lane = t & 63, wid = t >> 6;
        const int wr = wid >> 1, wc = wid & 1;
        const int cl = lane & 15, g = lane >> 4;
        f32x4 acc[4][2] = {};
        for (int n0 = 0; n0 < N_NODES; n0 += 64) {
            // A: M[n0+k][i0+c] -> GAs[c][k]   (64 x 128 source, transposed)
            #pragma unroll
            for (int pass = 0; pass < 8; ++pass) {
                int k = pass * 8 + (t >> 5), c4 = (t & 31) * 4;
                float4 v = *(const float4*)(Mf + (size_t)(n0 + k) * N_PIPES + i0 + c4);
                GAs[c4 + 0][k] = (f16)v.x; GAs[c4 + 1][k] = (f16)v.y;
                GAs[c4 + 2][k] = (f16)v.z; GAs[c4 + 3][k] = (f16)v.w;
            }
            // B: inv[n0+k][p0+c] -> GBs[c][k] (64 x 64 source, transposed)
            #pragma unroll
            for (int pass = 0; pass < 4; ++pass) {
                int k = pass * 16 + (t >> 4), c4 = (t & 15) * 4;
                float4 w = *(const float4*)(inv + (size_t)(n0 + k) * N_PIPES + p0 + c4);
                GBs[c4 + 0][k] = (f16)w.x; GBs[c4 + 1][k] = (f16)w.y;
                GBs[c4 + 2][k] = (f16)w.z; GBs[c4 + 3][k] = (f16)w.w;
            }
            __syncthreads();
            #pragma unroll
            for (int kk = 0; kk < 2; ++kk) {
                const int kb = kk * 32 + g * 8;
                f16x8 a[4], bfr[2];
                #pragma unroll
                for (int m = 0; m < 4; ++m) a[m] = *(const f16x8*)&GAs[wr * 64 + m * 16 + cl][kb];
                #pragma unroll
                for (int n = 0; n < 2; ++n) bfr[n] = *(const f16x8*)&GBs[wc * 32 + n * 16 + cl][kb];
                #pragma unroll
                for (int m = 0; m < 4; ++m)
                    #pragma unroll
                    for (int n = 0; n < 2; ++n)
                        acc[m][n] = __builtin_amdgcn_mfma_f32_16x16x32_f16(a[m], bfr[n], acc[m][n], 0, 0, 0);
            }
            __syncthreads();
        }
        #pragma unroll
        for (int m = 0; m < 4; ++m)
            #pragma unroll
            for (int reg = 0; reg < 4; ++reg) {
                const int row = i0 + wr * 64 + m * 16 + g * 4 + reg;
                #pragma unroll
                for (int n = 0; n < 2; ++n)
                    G16[(size_t)row * N_PIPES + p0 + wc * 32 + n * 16 + cl] = (f16)acc[m][n][reg];
            }
    }
}

// ======================= gemm_qt + riders (512 thr) ============================
// y<128:        qt tiles: q = D8*IDXT8^T (bf8, BK=128) + nv*G16[idx]; t8 = bf8(...)
// y in [128,136): G2[i][n] = sum_p G16[i][p]*A016[n][p]   (K=1024, f16 -> f16)
// y in [136,140): P1p[n][j] = sum_p A016[n][p]*DI16[j][p] - I  (K=1024, f16 -> bf8)
__global__ __launch_bounds__(512, 4) void gemm_qt_mfma(
    const unsigned char* __restrict__ D8, const int* __restrict__ leak_id,
    const unsigned char* __restrict__ IDXT8, const float* __restrict__ net,
    const f16* __restrict__ G16, const float* __restrict__ lKc,
    const float* __restrict__ supply, unsigned char* __restrict__ t8,
    const f16* __restrict__ A016, const f16* __restrict__ DI16,
    f16* __restrict__ G2out, unsigned char* __restrict__ P1p8,
    const int* __restrict__ dmap)
{
    __shared__ __align__(16) unsigned char As[2][128 * 128];   // 32 KB
    __shared__ __align__(16) unsigned char Bs[2][128 * 128];   // 32 KB
    const int t = threadIdx.x, lane = t & 63, wid = t >> 6;

    if (blockIdx.y >= 128) {     // ---------------- f16 rider GEMMs ----------------
        const f16 *Ar, *Br; f16* Cf; unsigned char* C8; const int* dm;
        int m0, ldc;
        const int c0 = blockIdx.x * 64;
        if (blockIdx.y < 136) {          // G2
            m0 = ((int)blockIdx.y - 128) * 128;
            Ar = G16; Br = A016; Cf = G2out; C8 = nullptr; dm = nullptr; ldc = N_NODES;
        } else {                         // P1p (512x256: 4 m-tiles x 4 c-tiles)
            if ((int)blockIdx.x >= 4) return;
            m0 = ((int)blockIdx.y - 136) * 128;
            Ar = A016; Br = DI16; Cf = nullptr; C8 = P1p8; dm = dmap; ldc = N_DEM;
        }
        f16 (*A2)[72] = (f16(*)[72])&Bs[0][0];
        f16 (*B2)[72] = (f16(*)[72])&As[0][0];
        const int wr = wid >> 2, wc = wid & 3;
        const int cl = lane & 15, g = lane >> 4;
        f32x4 acc[4] = {};
        for (int k0 = 0; k0 < 1024; k0 += 64) {
            {
                int r = t >> 2, c16 = (t & 3) * 16;
                *(f16x8*)&A2[r][c16]     = *(const f16x8*)(Ar + (size_t)(m0 + r) * N_PIPES + k0 + c16);
                *(f16x8*)&A2[r][c16 + 8] = *(const f16x8*)(Ar + (size_t)(m0 + r) * N_PIPES + k0 + c16 + 8);
                int r2 = t >> 3, c8 = (t & 7) * 8;
                *(f16x8*)&B2[r2][c8] = *(const f16x8*)(Br + (size_t)(c0 + r2) * N_PIPES + k0 + c8);
            }
            __syncthreads();
            #pragma unroll
            for (int kk = 0; kk < 2; ++kk) {
                const int kb = kk * 32 + g * 8;
                f16x8 b = *(const f16x8*)&B2[wc * 16 + cl][kb];
                #pragma unroll
                for (int m = 0; m < 4; ++m) {
                    f16x8 a = *(const f16x8*)&A2[wr * 64 + m * 16 + cl][kb];
                    acc[m] = __builtin_amdgcn_mfma_f32_16x16x32_f16(a, b, acc[m], 0, 0, 0);
                }
            }
            __syncthreads();
        }
        #pragma unroll
        for (int m = 0; m < 4; ++m)
            #pragma unroll
            for (int reg = 0; reg < 4; ++reg) {
                const int row = m0 + wr * 64 + m * 16 + g * 4 + reg;
                const int col = c0 + wc * 16 + cl;
                float v = acc[m][reg];
                if (dm && dm[col] == row) v -= 1.0f;
                if (C8) C8[(size_t)row * ldc + col] = f32_to_bf8(v);
                else    Cf[(size_t)row * ldc + col] = (f16)v;
            }
        return;
    }
    // ---------------- qt tiles (bf8, BK=128, 2 K-steps) ----------------
    const int bid = blockIdx.y * 8 + blockIdx.x;           // 1024 blocks
    const int w = (bid & 7) * 128 + (bid >> 3);            // XCD-contiguous
    const int bx = w & 7, by = w >> 3;
    const int p0 = bx * 128, sb = by * 128;
    const int wr = wid >> 2, wc = wid & 3;                 // 2 x 4 waves
    const int cl = lane & 15, g = lane >> 4;
    const int swrow = lane >> 3;
    const int swb = ((lane & 7) ^ swrow) * 16;             // 16B-granule byte swizzle

    const unsigned char* Abase = D8    + (size_t)(sb + swrow) * N_DEM + swb;
    const unsigned char* Bbase = IDXT8 + (size_t)(p0 + swrow) * N_DEM + swb;

    f32x4 acc[4][2] = {};
    auto stage = [&](int buf, int k0) {
        #pragma unroll
        for (int c = 0; c < 2; ++c) {
            int r0 = wid * 16 + c * 8;
            GLOAD16(Abase + (size_t)r0 * N_DEM + k0, &As[buf][r0 * 128]);
        }
        #pragma unroll
        for (int c = 0; c < 2; ++c) {
            int r0 = wid * 16 + c * 8;
            GLOAD16(Bbase + (size_t)r0 * N_DEM + k0, &Bs[buf][r0 * 128]);
        }
    };
    auto compute = [&](int buf) {
        #pragma unroll
        for (int ks = 0; ks < 4; ++ks) {
            const int bo = (ks * 32 + g * 8) ^ ((cl & 7) << 4);
            long long a[4], b[2];
            #pragma unroll
            for (int m = 0; m < 4; ++m)
                a[m] = *(const long long*)&As[buf][(wr * 64 + m * 16 + cl) * 128 + bo];
            #pragma unroll
            for (int n = 0; n < 2; ++n)
                b[n] = *(const long long*)&Bs[buf][(wc * 32 + n * 16 + cl) * 128 + bo];
            #pragma unroll
            for (int m = 0; m < 4; ++m)
                #pragma unroll
                for (int n = 0; n < 2; ++n)
                    acc[m][n] = __builtin_amdgcn_mfma_f32_16x16x32_bf8_bf8(a[m], b[n], acc[m][n], 0, 0, 0);
        }
    };

    stage(0, 0);
    stage(1, 128);
    WAITN(4); SBAR();
    compute(0);
    FENCE(); SBAR();
    WAITN(0); SBAR();
    compute(1);

    float lKc2[2], sup2[2]; int pcol[2];
    #pragma unroll
    for (int n = 0; n < 2; ++n) {
        pcol[n] = p0 + wc * 32 + n * 16 + cl;
        lKc2[n] = lKc[pcol[n]]; sup2[n] = supply[pcol[n]];
    }
    #pragma unroll
    for (int m = 0; m < 4; ++m) {
        #pragma unroll
        for (int reg = 0; reg < 4; ++reg) {
            const int srow = sb + wr * 64 + m * 16 + g * 4 + reg;
            const int idx = leak_id[srow];
            const float nv = net[idx];
            #pragma unroll
            for (int n = 0; n < 2; ++n) {
                float qv = acc[m][n][reg] + nv * (float)G16[(size_t)idx * N_PIPES + pcol[n]];
                float l = __builtin_amdgcn_logf(fabsf(qv));
                float hL = copysignf(__builtin_amdgcn_exp2f(fmaf(1.852f, l, lKc2[n])), qv);
                t8[(size_t)srow * N_PIPES + pcol[n]] = f32_to_bf8((sup2[n] - hL) * (1.0f / T_SCALE));
            }
        }
    }
}

// ======================= gemm_res (128x128, 8 waves, dbuf, bf8) ================
// accH = t8*inv8^T (K=1024, bf8, BK=128, 8 steps); accR = D8*P1p8^T (K=256, bf8, 2 steps)
__global__ __launch_bounds__(512, 4) void gemm_res_mfma(
    const unsigned char* __restrict__ t8, const unsigned char* __restrict__ inv8,
    const unsigned char* __restrict__ D8, const unsigned char* __restrict__ P1p8,
    const f16* __restrict__ MT16, const f16* __restrict__ G2_16,
    const int* __restrict__ leak_id, const float* __restrict__ net,
    const float* __restrict__ Cd_p, const float* __restrict__ a_p,
    float scale, float* __restrict__ out)
{
    __shared__ __align__(16) unsigned char AsM[2][128 * 128];  // 32 KB
    __shared__ __align__(16) unsigned char BsM[2][128 * 128];  // 32 KB
    const int nwg = gridDim.x * gridDim.y;
    const int bid = blockIdx.y * gridDim.x + blockIdx.x;
    const int w = (bid & 7) * (nwg >> 3) + (bid >> 3);
    const int bx = w % gridDim.x, by = w / gridDim.x;
    const int n0 = bx * 128, sb = by * 128;
    const int t = threadIdx.x, lane = t & 63, wid = t >> 6;
    const int wr = wid >> 2, wc = wid & 3;
    const int cl = lane & 15, g = lane >> 4;
    const int swrow = lane >> 3;
    const int swb = ((lane & 7) ^ swrow) * 16;     // byte swizzle, 16B granule

    const unsigned char* HAb = t8   + (size_t)(sb + swrow) * N_PIPES + swb;
    const unsigned char* HBb = inv8 + (size_t)(n0 + swrow) * N_PIPES + swb;
    const unsigned char* RAb = D8   + (size_t)(sb + swrow) * N_DEM + swb;
    const unsigned char* RBb = P1p8 + (size_t)(n0 + swrow) * N_DEM + swb;

    f32x4 accH[4][2] = {}, accR[4][2] = {};

    auto stageH = [&](int buf, int k0) {
        #pragma unroll
        for (int c = 0; c < 2; ++c) {
            int r0 = wid * 16 + c * 8;
            GLOAD16(HAb + (size_t)r0 * N_PIPES + k0, &AsM[buf][r0 * 128]);
        }
        #pragma unroll
        for (int c = 0; c < 2; ++c) {
            int r0 = wid * 16 + c * 8;
            GLOAD16(HBb + (size_t)r0 * N_PIPES + k0, &BsM[buf][r0 * 128]);
        }
    };
    auto stageR = [&](int buf, int k0) {
        #pragma unroll
        for (int c = 0; c < 2; ++c) {
            int r0 = wid * 16 + c * 8;
            GLOAD16(RAb + (size_t)r0 * N_DEM + k0, &AsM[buf][r0 * 128]);
        }
        #pragma unroll
        for (int c = 0; c < 2; ++c) {
            int r0 = wid * 16 + c * 8;
            GLOAD16(RBb + (size_t)r0 * N_DEM + k0, &BsM[buf][r0 * 128]);
        }
    };
    auto computeT = [&](int buf, f32x4 (&accA)[4][2]) {
        #pragma unroll
        for (int ks = 0; ks < 4; ++ks) {
            const int bo = (ks * 32 + g * 8) ^ ((cl & 7) << 4);
            long long a[4], b[2];
            #pragma unroll
            for (int m = 0; m < 4; ++m)
                a[m] = *(const long long*)&AsM[buf][(wr * 64 + m * 16 + cl) * 128 + bo];
            #pragma unroll
            for (int n = 0; n < 2; ++n)
                b[n] = *(const long long*)&BsM[buf][(wc * 32 + n * 16 + cl) * 128 + bo];
            #pragma unroll
            for (int m = 0; m < 4; ++m)
                #pragma unroll
                for (int n = 0; n < 2; ++n)
                    accA[m][n] = __builtin_amdgcn_mfma_f32_16x16x32_bf8_bf8(a[m], b[n], accA[m][n], 0, 0, 0);
        }
    };

    int cur = 0;
    stageH(0, 0);
    #pragma unroll 1
    for (int k = 0; k < 7; ++k) {
        stageH(cur ^ 1, (k + 1) * 128);
        WAITN(4); SBAR();
        computeT(cur, accH);
        FENCE(); SBAR();
        cur ^= 1;
    }
    // last H iter: prefetch first R tile into the other buffer
    stageR(cur ^ 1, 0);
    WAITN(4); SBAR();
    computeT(cur, accH);
    FENCE(); SBAR();
    cur ^= 1;
    // R: 2 K-steps (BK=128 of K=256)
    stageR(cur ^ 1, 128);
    WAITN(4); SBAR();
    computeT(cur, accR);
    FENCE(); SBAR();
    cur ^= 1;
    WAITN(0); SBAR();
    computeT(cur, accR);

    const float cda = Cd_p[0] * a_p[0] * sqrtf(2.f * 9.80665f);
    int node[2];
    #pragma unroll
    for (int n = 0; n < 2; ++n) node[n] = n0 + wc * 32 + n * 16 + cl;
    float lsum = 0.f;
    #pragma unroll
    for (int m = 0; m < 4; ++m) {
        #pragma unroll
        for (int reg = 0; reg < 4; ++reg) {
            const int srow = sb + wr * 64 + m * 16 + g * 4 + reg;
            const int idx = leak_id[srow];
            const float nv = net[idx];
            #pragma unroll
            for (int n = 0; n < 2; ++n) {
                const float H = accH[m][n][reg] * T_SCALE;
                const float sq = (H > 0.f) ? sqrtf(H) : 0.f;
                const float dl = cda * (float)MT16[(size_t)idx * N_NODES + node[n]] * sq;
                const float r = accR[m][n][reg] + nv * (float)G2_16[(size_t)idx * N_NODES + node[n]] - dl;
                lsum += r * r;
            }
        }
    }
    #pragma unroll
    for (int off = 32; off > 0; off >>= 1) lsum += __shfl_down(lsum, off, 64);
    __syncthreads();
    float* wred = (float*)&AsM[0][0];
    if (lane == 0) wred[wid] = lsum;
    __syncthreads();
    if (t == 0) {
        float tot = 0.f;
        #pragma unroll
        for (int i = 0; i < 8; ++i) tot += wred[i];
        atomicAdd(out, tot * scale);
    }
}

extern "C" void kernel_launch(void* const* d_in, const int* in_sizes, int n_in,
                              void* d_out, int out_size, void* d_ws, size_t ws_size,
                              hipStream_t stream) {
    const float* D          = (const float*)d_in[0];
    const int*   leak_id    = (const int*)  d_in[1];
    const float* A0         = (const float*)d_in[2];
    const float* inv        = (const float*)d_in[3];
    const float* M          = (const float*)d_in[4];
    const float* supply     = (const float*)d_in[5];
    const float* L          = (const float*)d_in[6];
    const float* dpipe      = (const float*)d_in[7];
    const float* C          = (const float*)d_in[8];
    const float* a_p        = (const float*)d_in[9];
    const float* Cd_p       = (const float*)d_in[10];
    const float* W1         = (const float*)d_in[11];
    const float* b1         = (const float*)d_in[12];
    const float* W2         = (const float*)d_in[13];
    const float* b2         = (const float*)d_in[14];
    const float* W3         = (const float*)d_in[15];
    const float* b3         = (const float*)d_in[16];
    const float* base       = (const float*)d_in[17];
    const int*   demand_idx = (const int*)  d_in[18];

    char* ws = (char*)d_ws;
    size_t off = 0;
    auto carve = [&](size_t bytes) { char* p = ws + off; off += (bytes + 255) & ~(size_t)255; return p; };
    float* net    = (float*)carve(N_PIPES * 4);
    float* lKc    = (float*)carve(N_PIPES * 4);
    unsigned char* inv8 = (unsigned char*)carve((size_t)N_NODES * N_PIPES);
    f16* A016   = (f16*)carve((size_t)N_NODES * N_PIPES * 2);
    f16* MT16   = (f16*)carve((size_t)N_PIPES * N_NODES * 2);
    f16* G16    = (f16*)carve((size_t)N_PIPES * N_PIPES * 2);
    f16* G2_16  = (f16*)carve((size_t)N_PIPES * N_NODES * 2);
    unsigned char* P1p8 = (unsigned char*)carve((size_t)N_NODES * N_DEM);
    f16* DI16   = (f16*)carve((size_t)N_DEM * N_PIPES * 2);
    unsigned char* IDXT8 = (unsigned char*)carve((size_t)N_PIPES * N_DEM);
    unsigned char* D8    = (unsigned char*)carve((size_t)S_TOTAL * N_DEM);
    unsigned char* t8    = (unsigned char*)carve((size_t)S_TOTAL * N_PIPES);

    // ---- dispatch 1: all prep incl. G16 (also zeroes d_out) ----
    prep_all<<<1280, 256, 0, stream>>>(
        W1, b1, W2, b2, W3, b3, base, L, dpipe, C,
        M, inv, A0, D, demand_idx,
        net, lKc, MT16, inv8, A016, D8, DI16, IDXT8, G16,
        (float*)d_out, out_size);

    // ---- dispatch 2: qt (1024 blocks, bf8) + G2 rider (64) + P1p rider (16) ----
    gemm_qt_mfma<<<dim3(8, 140), 512, 0, stream>>>(
        D8, leak_id, IDXT8, net, G16, lKc, supply, t8,
        A016, DI16, G2_16, P1p8, demand_idx);

    // ---- dispatch 3: res (all-bf8 GEMM phases) ----
    const float scale = 1.f / ((float)S_TOTAL * (float)N_NODES);
    gemm_res_mfma<<<dim3(N_NODES / 128, S_TOTAL / 128), 512, 0, stream>>>(
        t8, inv8, D8, P1p8, MT16, G2_16, leak_id, net, Cd_p, a_p,
        scale, (float*)d_out);
}

// Round 19
// 84.684 us; speedup vs baseline: 1.2855x; 1.2855x over previous
//
#include <hip/hip_runtime.h>
#include <math.h>

typedef _Float16 f16;
typedef _Float16 f16x4 __attribute__((ext_vector_type(4)));
typedef _Float16 f16x8 __attribute__((ext_vector_type(8)));
typedef float f32x4 __attribute__((ext_vector_type(4)));

#define S_TOTAL 16384
#define N_NODES 512
#define N_PIPES 1024
#define N_DEM   256
#define HIDDEN  64
#define T_SCALE 256.0f   // t = (supply - hL)/T_SCALE; H *= T_SCALE

// direct HBM -> LDS, 16B per lane (wave writes base + lane*16, LINEAR dest)
#define GLOAD16(gsrc, ldst) \
    __builtin_amdgcn_global_load_lds((const __attribute__((address_space(1))) void*)(gsrc), \
                                     (__attribute__((address_space(3))) void*)(ldst), 16, 0, 0)
#define SBAR()  __builtin_amdgcn_s_barrier()
#define FENCE() asm volatile("" ::: "memory")
#define WAITN(n) asm volatile("s_waitcnt vmcnt(" #n ")" ::: "memory")

// f32 -> fp8 e5m2 (bf8): RNE to high byte of f16 bit pattern
__device__ __forceinline__ unsigned char f32_to_bf8(float x) {
    unsigned short h = __builtin_bit_cast(unsigned short, (f16)x);
    unsigned short r = (unsigned short)(h + 0x7F + ((h >> 8) & 1));
    return (unsigned char)(r >> 8);
}

// ================= fused prep: MLP + transposes + conversions + gathers ========
__global__ __launch_bounds__(256) void prep_all(
    const float* __restrict__ W1, const float* __restrict__ b1,
    const float* __restrict__ W2, const float* __restrict__ b2,
    const float* __restrict__ W3, const float* __restrict__ b3,
    const float* __restrict__ base,
    const float* __restrict__ L, const float* __restrict__ dpipe,
    const float* __restrict__ Cw,
    const float* __restrict__ Mf, const float* __restrict__ inv,
    const float* __restrict__ A0, const float* __restrict__ D,
    const int* __restrict__ dmap,
    float* __restrict__ net, float* __restrict__ lKc,
    f16* __restrict__ MT16, f16* __restrict__ invT16,
    f16* __restrict__ inv16, unsigned char* __restrict__ inv8,
    f16* __restrict__ A016, unsigned char* __restrict__ D8,
    f16* __restrict__ DI16, unsigned char* __restrict__ IDXT8,
    float* __restrict__ out, int out_size)
{
    __shared__ __align__(16) f16 tile[64][72];
    const int b = blockIdx.x, t = threadIdx.x;
    if (b < 256) {
        if (b == 0) for (int i = t; i < out_size; i += 256) out[i] = 0.f;
        const int wid = t >> 6, k = t & 63;
        const int p = b * 4 + wid;
        const float x = (float)p;
        float h1 = tanhf(x * W1[k] + b1[k]);
        float acc = b2[k];
        #pragma unroll
        for (int j = 0; j < HIDDEN; ++j) {
            float hj = __shfl(h1, j, 64);
            acc = fmaf(hj, W2[j * HIDDEN + k], acc);
        }
        float partial = tanhf(acc) * W3[k];
        #pragma unroll
        for (int off = 32; off > 0; off >>= 1) partial += __shfl_down(partial, off, 64);
        if (k == 0) {
            net[p] = base[p] + partial + b3[0];
            lKc[p] = log2f(10.667f) - 1.852f * log2f(Cw[p]) - 4.871f * log2f(dpipe[p]) + log2f(L[p]);
        }
        return;
    }
    if (b < 512) {
        const int idx = b - 256;
        const float* in = (idx < 128) ? Mf : inv;
        f16* outp = (idx < 128) ? MT16 : invT16;
        const int i2 = idx & 127;
        const int bx = i2 & 15, by = i2 >> 4;
        const int r0 = by * 64, c0 = bx * 64;
        const int lr = t / 16, lc4 = (t % 16) * 4;
        #pragma unroll
        for (int i = 0; i < 4; ++i) {
            int r = lr + i * 16;
            float4 v = *(const float4*)(in + (size_t)(r0 + r) * N_PIPES + c0 + lc4);
            tile[lc4 + 0][r] = (f16)v.x; tile[lc4 + 1][r] = (f16)v.y;
            tile[lc4 + 2][r] = (f16)v.z; tile[lc4 + 3][r] = (f16)v.w;
        }
        __syncthreads();
        const int wrow = t / 4, wc16 = (t % 4) * 16;
        *(f16x8*)(outp + (size_t)(c0 + wrow) * N_NODES + r0 + wc16)     = *(f16x8*)&tile[wrow][wc16];
        *(f16x8*)(outp + (size_t)(c0 + wrow) * N_NODES + r0 + wc16 + 8) = *(f16x8*)&tile[wrow][wc16 + 8];
        return;
    }
    const int tid = (b - 512) * 256 + t;
    const int np = 768 * 256;
    for (int i = tid; i < (N_NODES * N_PIPES) / 4; i += np) {
        float4 v = ((const float4*)inv)[i];
        ((f16x4*)inv16)[i] = (f16x4){(f16)v.x, (f16)v.y, (f16)v.z, (f16)v.w};
        uchar4 v8 = {f32_to_bf8(v.x), f32_to_bf8(v.y), f32_to_bf8(v.z), f32_to_bf8(v.w)};
        ((uchar4*)inv8)[i] = v8;
        float4 w = ((const float4*)A0)[i];
        ((f16x4*)A016)[i] = (f16x4){(f16)w.x, (f16)w.y, (f16)w.z, (f16)w.w};
    }
    for (int i = tid; i < (S_TOTAL * N_DEM) / 4; i += np) {
        float4 v = ((const float4*)D)[i];
        uchar4 o = {f32_to_bf8(v.x), f32_to_bf8(v.y), f32_to_bf8(v.z), f32_to_bf8(v.w)};
        ((uchar4*)D8)[i] = o;
    }
    for (int i = tid; i < N_DEM * (N_PIPES / 4); i += np) {
        int j = i >> 8, p0 = (i & 255) * 4;
        float4 v = *(const float4*)(inv + (size_t)dmap[j] * N_PIPES + p0);
        *(f16x4*)(DI16 + (size_t)j * N_PIPES + p0) = (f16x4){(f16)v.x, (f16)v.y, (f16)v.z, (f16)v.w};
    }
    for (int i = tid; i < N_PIPES * (N_DEM / 4); i += np) {
        int p = i >> 6, j0 = (i & 63) * 4;
        uchar4 o;
        #pragma unroll
        for (int u = 0; u < 4; ++u)
            o[u] = f32_to_bf8(inv[(size_t)dmap[j0 + u] * N_PIPES + p]);
        *(uchar4*)(IDXT8 + (size_t)p * N_DEM + j0) = o;
    }
}

// ---------------- small MFMA GEMM body (256 thr): C[i][c] = sum_k A[i][k]*B[c][k]
struct GemmP {
    const f16* A; int lda;
    const f16* B; int ldb;
    f16* C; int ldc;
    int K;
    const int* dmap;
    int gx, gy;
    unsigned char* C8;   // if non-null, write bf8 here instead of C
};

__device__ __forceinline__ void gemm_body(const GemmP& P, int bx, int by) {
    __shared__ __align__(16) f16 As[128][72], Bs[64][72];
    const int m0 = by * 128, c0 = bx * 64;
    const int t = threadIdx.x, lane = t & 63, wid = t >> 6;
    const int wr = wid >> 1, wc = wid & 1;
    const int cl = lane & 15, g = lane >> 4;
    const int tr = t >> 3, tc = (t & 7) * 8;
    f32x4 acc[4][2] = {};
    for (int k0 = 0; k0 < P.K; k0 += 64) {
        #pragma unroll
        for (int r = 0; r < 4; ++r) {
            int row = r * 32 + tr;
            *(f16x8*)&As[row][tc] = *(const f16x8*)(P.A + (size_t)(m0 + row) * P.lda + k0 + tc);
        }
        #pragma unroll
        for (int r = 0; r < 2; ++r) {
            int row = r * 32 + tr;
            *(f16x8*)&Bs[row][tc] = *(const f16x8*)(P.B + (size_t)(c0 + row) * P.ldb + k0 + tc);
        }
        __syncthreads();
        #pragma unroll
        for (int kk = 0; kk < 2; ++kk) {
            const int kb = kk * 32 + g * 8;
            f16x8 a[4], bfr[2];
            #pragma unroll
            for (int m = 0; m < 4; ++m) a[m] = *(const f16x8*)&As[wr * 64 + m * 16 + cl][kb];
            #pragma unroll
            for (int n = 0; n < 2; ++n) bfr[n] = *(const f16x8*)&Bs[wc * 32 + n * 16 + cl][kb];
            #pragma unroll
            for (int m = 0; m < 4; ++m)
                #pragma unroll
                for (int n = 0; n < 2; ++n)
                    acc[m][n] = __builtin_amdgcn_mfma_f32_16x16x32_f16(a[m], bfr[n], acc[m][n], 0, 0, 0);
        }
        __syncthreads();
    }
    #pragma unroll
    for (int m = 0; m < 4; ++m)
        #pragma unroll
        for (int reg = 0; reg < 4; ++reg) {
            const int row = m0 + wr * 64 + m * 16 + g * 4 + reg;
            #pragma unroll
            for (int n = 0; n < 2; ++n) {
                const int col = c0 + wc * 32 + n * 16 + cl;
                float v = acc[m][n][reg];
                if (P.dmap && P.dmap[col] == row) v -= 1.0f;
                if (P.C8) P.C8[(size_t)row * P.ldc + col] = f32_to_bf8(v);
                else      P.C [(size_t)row * P.ldc + col] = (f16)v;
            }
        }
}

__global__ __launch_bounds__(256) void gemm_small3(GemmP p0, GemmP p1, GemmP p2) {
    const GemmP& P = (blockIdx.z == 0) ? p0 : (blockIdx.z == 1) ? p1 : p2;
    if ((int)blockIdx.x >= P.gx || (int)blockIdx.y >= P.gy) return;
    gemm_body(P, blockIdx.x, blockIdx.y);
}

// ======================= gemm_qt + G2 rider (512 thr) ==========================
// y<128: q[s][p] = D8*IDXT8^T (bf8, BK=128) + nv*G16[idx]; t8 = bf8((supply-hL)/T_SCALE)
// y>=128: G2[i][c] = sum_k MT16[i][k]*Wt[c][k]  (1024x512, K=512, f16)
__global__ __launch_bounds__(512, 4) void gemm_qt_mfma(
    const unsigned char* __restrict__ D8, const int* __restrict__ leak_id,
    const unsigned char* __restrict__ IDXT8, const float* __restrict__ net,
    const f16* __restrict__ G16, const float* __restrict__ lKc,
    const float* __restrict__ supply, unsigned char* __restrict__ t8,
    const f16* __restrict__ MT16, const f16* __restrict__ Wt,
    f16* __restrict__ G2out)
{
    __shared__ __align__(16) unsigned char As[2][128 * 128];   // 32 KB
    __shared__ __align__(16) unsigned char Bs[2][128 * 128];   // 32 KB
    const int t = threadIdx.x, lane = t & 63, wid = t >> 6;

    if (blockIdx.y >= 128) {     // ---------------- G2 rider (f16) ----------------
        f16 (*A2)[72] = (f16(*)[72])&Bs[0][0];
        f16 (*B2)[72] = (f16(*)[72])&As[0][0];
        const int m0 = ((int)blockIdx.y - 128) * 128, c0 = blockIdx.x * 64;
        const int wr = wid >> 2, wc = wid & 3;
        const int cl = lane & 15, g = lane >> 4;
        f32x4 acc[4] = {};
        for (int k0 = 0; k0 < 512; k0 += 64) {
            {
                int r = t >> 2, c16 = (t & 3) * 16;
                *(f16x8*)&A2[r][c16]     = *(const f16x8*)(MT16 + (size_t)(m0 + r) * N_NODES + k0 + c16);
                *(f16x8*)&A2[r][c16 + 8] = *(const f16x8*)(MT16 + (size_t)(m0 + r) * N_NODES + k0 + c16 + 8);
                int r2 = t >> 3, c8 = (t & 7) * 8;
                *(f16x8*)&B2[r2][c8] = *(const f16x8*)(Wt + (size_t)(c0 + r2) * N_NODES + k0 + c8);
            }
            __syncthreads();
            #pragma unroll
            for (int kk = 0; kk < 2; ++kk) {
                const int kb = kk * 32 + g * 8;
                f16x8 b = *(const f16x8*)&B2[wc * 16 + cl][kb];
                #pragma unroll
                for (int m = 0; m < 4; ++m) {
                    f16x8 a = *(const f16x8*)&A2[wr * 64 + m * 16 + cl][kb];
                    acc[m] = __builtin_amdgcn_mfma_f32_16x16x32_f16(a, b, acc[m], 0, 0, 0);
                }
            }
            __syncthreads();
        }
        #pragma unroll
        for (int m = 0; m < 4; ++m)
            #pragma unroll
            for (int reg = 0; reg < 4; ++reg)
                G2out[(size_t)(m0 + wr * 64 + m * 16 + g * 4 + reg) * N_NODES + c0 + wc * 16 + cl] = (f16)acc[m][reg];
        return;
    }
    // ---------------- qt tiles (bf8, BK=128, 2 K-steps) ----------------
    const int bid = blockIdx.y * 8 + blockIdx.x;           // 1024 blocks
    const int w = (bid & 7) * 128 + (bid >> 3);            // XCD-contiguous
    const int bx = w & 7, by = w >> 3;
    const int p0 = bx * 128, sb = by * 128;
    const int wr = wid >> 2, wc = wid & 3;                 // 2 x 4 waves
    const int cl = lane & 15, g = lane >> 4;
    const int swrow = lane >> 3;
    const int swb = ((lane & 7) ^ swrow) * 16;             // 16B-granule byte swizzle

    const unsigned char* Abase = D8    + (size_t)(sb + swrow) * N_DEM + swb;
    const unsigned char* Bbase = IDXT8 + (size_t)(p0 + swrow) * N_DEM + swb;

    f32x4 acc[4][2] = {};
    auto stage = [&](int buf, int k0) {
        #pragma unroll
        for (int c = 0; c < 2; ++c) {
            int r0 = wid * 16 + c * 8;
            GLOAD16(Abase + (size_t)r0 * N_DEM + k0, &As[buf][r0 * 128]);
        }
        #pragma unroll
        for (int c = 0; c < 2; ++c) {
            int r0 = wid * 16 + c * 8;
            GLOAD16(Bbase + (size_t)r0 * N_DEM + k0, &Bs[buf][r0 * 128]);
        }
    };
    auto compute = [&](int buf) {
        #pragma unroll
        for (int ks = 0; ks < 4; ++ks) {
            const int bo = (ks * 32 + g * 8) ^ ((cl & 7) << 4);
            long long a[4], b[2];
            #pragma unroll
            for (int m = 0; m < 4; ++m)
                a[m] = *(const long long*)&As[buf][(wr * 64 + m * 16 + cl) * 128 + bo];
            #pragma unroll
            for (int n = 0; n < 2; ++n)
                b[n] = *(const long long*)&Bs[buf][(wc * 32 + n * 16 + cl) * 128 + bo];
            #pragma unroll
            for (int m = 0; m < 4; ++m)
                #pragma unroll
                for (int n = 0; n < 2; ++n)
                    acc[m][n] = __builtin_amdgcn_mfma_f32_16x16x32_bf8_bf8(a[m], b[n], acc[m][n], 0, 0, 0);
        }
    };

    stage(0, 0);
    stage(1, 128);
    WAITN(4); SBAR();
    compute(0);
    FENCE(); SBAR();
    WAITN(0); SBAR();
    compute(1);

    float lKc2[2], sup2[2]; int pcol[2];
    #pragma unroll
    for (int n = 0; n < 2; ++n) {
        pcol[n] = p0 + wc * 32 + n * 16 + cl;
        lKc2[n] = lKc[pcol[n]]; sup2[n] = supply[pcol[n]];
    }
    #pragma unroll
    for (int m = 0; m < 4; ++m) {
        #pragma unroll
        for (int reg = 0; reg < 4; ++reg) {
            const int srow = sb + wr * 64 + m * 16 + g * 4 + reg;
            const int idx = leak_id[srow];
            const float nv = net[idx];
            #pragma unroll
            for (int n = 0; n < 2; ++n) {
                float qv = acc[m][n][reg] + nv * (float)G16[(size_t)idx * N_PIPES + pcol[n]];
                float l = __builtin_amdgcn_logf(fabsf(qv));
                float hL = copysignf(__builtin_amdgcn_exp2f(fmaf(1.852f, l, lKc2[n])), qv);
                t8[(size_t)srow * N_PIPES + pcol[n]] = f32_to_bf8((sup2[n] - hL) * (1.0f / T_SCALE));
            }
        }
    }
}

// ======================= gemm_res (128x128, 8 waves, dbuf, bf8) ================
// accH = t8*inv8^T (K=1024, bf8, BK=128, 8 steps); accR = D8*P1p8^T (K=256, bf8, 2 steps)
__global__ __launch_bounds__(512, 4) void gemm_res_mfma(
    const unsigned char* __restrict__ t8, const unsigned char* __restrict__ inv8,
    const unsigned char* __restrict__ D8, const unsigned char* __restrict__ P1p8,
    const f16* __restrict__ MT16, const f16* __restrict__ G2_16,
    const int* __restrict__ leak_id, const float* __restrict__ net,
    const float* __restrict__ Cd_p, const float* __restrict__ a_p,
    float scale, float* __restrict__ out)
{
    __shared__ __align__(16) unsigned char AsM[2][128 * 128];  // 32 KB
    __shared__ __align__(16) unsigned char BsM[2][128 * 128];  // 32 KB
    const int nwg = gridDim.x * gridDim.y;
    const int bid = blockIdx.y * gridDim.x + blockIdx.x;
    const int w = (bid & 7) * (nwg >> 3) + (bid >> 3);
    const int bx = w % gridDim.x, by = w / gridDim.x;
    const int n0 = bx * 128, sb = by * 128;
    const int t = threadIdx.x, lane = t & 63, wid = t >> 6;
    const int wr = wid >> 2, wc = wid & 3;
    const int cl = lane & 15, g = lane >> 4;
    const int swrow = lane >> 3;
    const int swb = ((lane & 7) ^ swrow) * 16;     // byte swizzle, 16B granule

    const unsigned char* HAb = t8   + (size_t)(sb + swrow) * N_PIPES + swb;
    const unsigned char* HBb = inv8 + (size_t)(n0 + swrow) * N_PIPES + swb;
    const unsigned char* RAb = D8   + (size_t)(sb + swrow) * N_DEM + swb;
    const unsigned char* RBb = P1p8 + (size_t)(n0 + swrow) * N_DEM + swb;

    f32x4 accH[4][2] = {}, accR[4][2] = {};

    auto stageH = [&](int buf, int k0) {
        #pragma unroll
        for (int c = 0; c < 2; ++c) {
            int r0 = wid * 16 + c * 8;
            GLOAD16(HAb + (size_t)r0 * N_PIPES + k0, &AsM[buf][r0 * 128]);
        }
        #pragma unroll
        for (int c = 0; c < 2; ++c) {
            int r0 = wid * 16 + c * 8;
            GLOAD16(HBb + (size_t)r0 * N_PIPES + k0, &BsM[buf][r0 * 128]);
        }
    };
    auto stageR = [&](int buf, int k0) {
        #pragma unroll
        for (int c = 0; c < 2; ++c) {
            int r0 = wid * 16 + c * 8;
            GLOAD16(RAb + (size_t)r0 * N_DEM + k0, &AsM[buf][r0 * 128]);
        }
        #pragma unroll
        for (int c = 0; c < 2; ++c) {
            int r0 = wid * 16 + c * 8;
            GLOAD16(RBb + (size_t)r0 * N_DEM + k0, &BsM[buf][r0 * 128]);
        }
    };
    auto computeT = [&](int buf, f32x4 (&accA)[4][2]) {
        #pragma unroll
        for (int ks = 0; ks < 4; ++ks) {
            const int bo = (ks * 32 + g * 8) ^ ((cl & 7) << 4);
            long long a[4], b[2];
            #pragma unroll
            for (int m = 0; m < 4; ++m)
                a[m] = *(const long long*)&AsM[buf][(wr * 64 + m * 16 + cl) * 128 + bo];
            #pragma unroll
            for (int n = 0; n < 2; ++n)
                b[n] = *(const long long*)&BsM[buf][(wc * 32 + n * 16 + cl) * 128 + bo];
            #pragma unroll
            for (int m = 0; m < 4; ++m)
                #pragma unroll
                for (int n = 0; n < 2; ++n)
                    accA[m][n] = __builtin_amdgcn_mfma_f32_16x16x32_bf8_bf8(a[m], b[n], accA[m][n], 0, 0, 0);
        }
    };

    int cur = 0;
    stageH(0, 0);
    #pragma unroll 1
    for (int k = 0; k < 7; ++k) {
        stageH(cur ^ 1, (k + 1) * 128);
        WAITN(4); SBAR();
        computeT(cur, accH);
        FENCE(); SBAR();
        cur ^= 1;
    }
    // last H iter: prefetch first R tile into the other buffer
    stageR(cur ^ 1, 0);
    WAITN(4); SBAR();
    computeT(cur, accH);
    FENCE(); SBAR();
    cur ^= 1;
    // R: 2 K-steps (BK=128 of K=256)
    stageR(cur ^ 1, 128);
    WAITN(4); SBAR();
    computeT(cur, accR);
    FENCE(); SBAR();
    cur ^= 1;
    WAITN(0); SBAR();
    computeT(cur, accR);

    const float cda = Cd_p[0] * a_p[0] * sqrtf(2.f * 9.80665f);
    int node[2];
    #pragma unroll
    for (int n = 0; n < 2; ++n) node[n] = n0 + wc * 32 + n * 16 + cl;
    float lsum = 0.f;
    #pragma unroll
    for (int m = 0; m < 4; ++m) {
        #pragma unroll
        for (int reg = 0; reg < 4; ++reg) {
            const int srow = sb + wr * 64 + m * 16 + g * 4 + reg;
            const int idx = leak_id[srow];
            const float nv = net[idx];
            #pragma unroll
            for (int n = 0; n < 2; ++n) {
                const float H = accH[m][n][reg] * T_SCALE;
                const float sq = (H > 0.f) ? sqrtf(H) : 0.f;
                const float dl = cda * (float)MT16[(size_t)idx * N_NODES + node[n]] * sq;
                const float r = accR[m][n][reg] + nv * (float)G2_16[(size_t)idx * N_NODES + node[n]] - dl;
                lsum += r * r;
            }
        }
    }
    #pragma unroll
    for (int off = 32; off > 0; off >>= 1) lsum += __shfl_down(lsum, off, 64);
    __syncthreads();
    float* wred = (float*)&AsM[0][0];
    if (lane == 0) wred[wid] = lsum;
    __syncthreads();
    if (t == 0) {
        float tot = 0.f;
        #pragma unroll
        for (int i = 0; i < 8; ++i) tot += wred[i];
        atomicAdd(out, tot * scale);
    }
}

extern "C" void kernel_launch(void* const* d_in, const int* in_sizes, int n_in,
                              void* d_out, int out_size, void* d_ws, size_t ws_size,
                              hipStream_t stream) {
    const float* D          = (const float*)d_in[0];
    const int*   leak_id    = (const int*)  d_in[1];
    const float* A0         = (const float*)d_in[2];
    const float* inv        = (const float*)d_in[3];
    const float* M          = (const float*)d_in[4];
    const float* supply     = (const float*)d_in[5];
    const float* L          = (const float*)d_in[6];
    const float* dpipe      = (const float*)d_in[7];
    const float* C          = (const float*)d_in[8];
    const float* a_p        = (const float*)d_in[9];
    const float* Cd_p       = (const float*)d_in[10];
    const float* W1         = (const float*)d_in[11];
    const float* b1         = (const float*)d_in[12];
    const float* W2         = (const float*)d_in[13];
    const float* b2         = (const float*)d_in[14];
    const float* W3         = (const float*)d_in[15];
    const float* b3         = (const float*)d_in[16];
    const float* base       = (const float*)d_in[17];
    const int*   demand_idx = (const int*)  d_in[18];

    char* ws = (char*)d_ws;
    size_t off = 0;
    auto carve = [&](size_t bytes) { char* p = ws + off; off += (bytes + 255) & ~(size_t)255; return p; };
    float* net    = (float*)carve(N_PIPES * 4);
    float* lKc    = (float*)carve(N_PIPES * 4);
    f16* inv16  = (f16*)carve((size_t)N_NODES * N_PIPES * 2);
    unsigned char* inv8 = (unsigned char*)carve((size_t)N_NODES * N_PIPES);
    f16* A016   = (f16*)carve((size_t)N_NODES * N_PIPES * 2);
    f16* MT16   = (f16*)carve((size_t)N_PIPES * N_NODES * 2);
    f16* invT16 = (f16*)carve((size_t)N_PIPES * N_NODES * 2);
    f16* G16    = (f16*)carve((size_t)N_PIPES * N_PIPES * 2);
    f16* G2_16  = (f16*)carve((size_t)N_PIPES * N_NODES * 2);
    f16* Wt     = (f16*)carve((size_t)N_NODES * N_NODES * 2);
    unsigned char* P1p8 = (unsigned char*)carve((size_t)N_NODES * N_DEM);
    f16* DI16   = (f16*)carve((size_t)N_DEM * N_PIPES * 2);
    unsigned char* IDXT8 = (unsigned char*)carve((size_t)N_PIPES * N_DEM);
    unsigned char* D8    = (unsigned char*)carve((size_t)S_TOTAL * N_DEM);
    unsigned char* t8    = (unsigned char*)carve((size_t)S_TOTAL * N_PIPES);

    // ---- dispatch 1: all prep (also zeroes d_out) ----
    prep_all<<<1280, 256, 0, stream>>>(
        W1, b1, W2, b2, W3, b3, base, L, dpipe, C,
        M, inv, A0, D, demand_idx,
        net, lKc, MT16, invT16, inv16, inv8, A016, D8, DI16, IDXT8,
        (float*)d_out, out_size);

    // ---- dispatch 2: three independent small GEMMs ----
    GemmP pG16 = {MT16, N_NODES, invT16, N_NODES, G16, N_PIPES, N_NODES, nullptr, 16, 8, nullptr};
    GemmP pWt  = {A016, N_PIPES, inv16, N_PIPES, Wt, N_NODES, N_PIPES, nullptr, 8, 4, nullptr};
    GemmP pP1  = {A016, N_PIPES, DI16, N_PIPES, nullptr, N_DEM, N_PIPES, demand_idx, 4, 4, P1p8};
    gemm_small3<<<dim3(16, 8, 3), 256, 0, stream>>>(pG16, pWt, pP1);

    // ---- dispatch 3: qt (1024 blocks, bf8) + G2 rider (64 blocks) ----
    gemm_qt_mfma<<<dim3(8, 136), 512, 0, stream>>>(
        D8, leak_id, IDXT8, net, G16, lKc, supply, t8, MT16, Wt, G2_16);

    // ---- dispatch 4: res (all-bf8 GEMM phases) ----
    const float scale = 1.f / ((float)S_TOTAL * (float)N_NODES);
    gemm_res_mfma<<<dim3(N_NODES / 128, S_TOTAL / 128), 512, 0, stream>>>(
        t8, inv8, D8, P1p8, MT16, G2_16, leak_id, net, Cd_p, a_p,
        scale, (float*)d_out);
}